// Round 16
// baseline (271.855 us; speedup 1.0000x reference)
//
#include <hip/hip_runtime.h>

typedef _Float16 f16;
typedef _Float16 f16x4 __attribute__((ext_vector_type(4)));
typedef _Float16 f16x8 __attribute__((ext_vector_type(8)));
typedef float f32x4 __attribute__((ext_vector_type(4)));

#define LOG2E 1.4426950408889634f
#define SCL   (1.4426950408889634f / 32.0f)   // SCALE^2 * log2(e) folded
#define TH_RAW 177.445f                        // 8.0 / SCL : defer-max threshold

// ---------------- K0: W[s][256][768] f32 -> Wt[s][512][256] f16 (Q|K cols) --
__global__ __launch_bounds__(256) void k_W(const float* __restrict__ Wq,
    const float* __restrict__ Wa, f16* __restrict__ Wt) {
  __shared__ f16 tile[64][65];
  int n0 = blockIdx.x * 64, k0 = blockIdx.y * 64, s = blockIdx.z;
  const float* W = s ? Wa : Wq;
  f16* dst = Wt + (size_t)s * 512 * 256;
  int t = threadIdx.x, c = t & 63, rg = t >> 6;
#pragma unroll
  for (int r = 0; r < 16; ++r) {
    int krow = r * 4 + rg;
    tile[krow][c] = (f16)W[(size_t)(k0 + krow) * 768 + n0 + c];
  }
  __syncthreads();
#pragma unroll
  for (int r = 0; r < 16; ++r) {
    int nrow = r * 4 + rg;
    dst[(size_t)(n0 + nrow) * 256 + k0 + c] = tile[c][nrow];
  }
}

// ---------------- K1: Q/K projections + x-transpose riders (R10-proven) -----
// bx<64: proj block (mt=bx, nt=by, s=bz). Out Q*/K* as [b*8+h][2048][32] f16.
// bx>=64: x-transpose rider: x[b][2048][256] f32 -> xt[b][256][2048] f16.
__global__ __launch_bounds__(256) void k_proj(const float* __restrict__ x,
    const float* __restrict__ af, const f16* __restrict__ Wt,
    f16* __restrict__ Qs, f16* __restrict__ Ks,
    f16* __restrict__ Qa, f16* __restrict__ Ka, f16* __restrict__ xt) {
  __shared__ f16 tile[64][65];
  int t = threadIdx.x;
  if (blockIdx.x >= 64) {
    // ---- x-transpose rider ----
    int r = ((blockIdx.z * 8 + blockIdx.y) * 16 + (blockIdx.x - 64));
    int n0 = (r & 31) * 64, d0 = ((r >> 5) & 3) * 64, b = r >> 7;
    int c = t & 63, rg = t >> 6;
#pragma unroll
    for (int rr = 0; rr < 16; ++rr) {
      int row = rr * 4 + rg;
      tile[row][c] = (f16)x[((size_t)b * 2048 + n0 + row) * 256 + d0 + c];
    }
    __syncthreads();
#pragma unroll
    for (int rr = 0; rr < 16; ++rr) {
      int drow = rr * 4 + rg;
      xt[((size_t)b * 256 + d0 + drow) * 2048 + n0 + c] = tile[c][drow];
    }
    return;
  }
  int mt = blockIdx.x, nt = blockIdx.y, s = blockIdx.z;
  const float* A = s ? af : x;
  const f16* W = Wt + (size_t)s * 512 * 256;
  f16* Qd = s ? Qa : Qs;
  f16* Kd = s ? Ka : Ks;
  int wv = t >> 6, ln = t & 63, cl = ln & 15, g = ln >> 4;
  int m0 = mt * 64, n0 = nt * 64;
  const float* arow = A + (size_t)(m0 + wv * 16 + cl) * 256 + g * 8;
  const f16* wb = W + (size_t)n0 * 256 + g * 8;
  f32x4 z4 = {0.f, 0.f, 0.f, 0.f};
  f32x4 acc[4] = {z4, z4, z4, z4};
#pragma unroll
  for (int k32 = 0; k32 < 8; ++k32) {
    float4 u = *(const float4*)(arow + k32 * 32);
    float4 v = *(const float4*)(arow + k32 * 32 + 4);
    f16x8 a = { (f16)u.x, (f16)u.y, (f16)u.z, (f16)u.w,
                (f16)v.x, (f16)v.y, (f16)v.z, (f16)v.w };
#pragma unroll
    for (int n4 = 0; n4 < 4; ++n4) {
      f16x8 bf = *(const f16x8*)(wb + (size_t)(n4 * 16 + cl) * 256 + k32 * 32);
      acc[n4] = __builtin_amdgcn_mfma_f32_16x16x32_f16(a, bf, acc[n4], 0, 0, 0);
    }
  }
#pragma unroll
  for (int n4 = 0; n4 < 4; ++n4) {
    int c = n0 + n4 * 16 + cl;               // 0..511 (Q: 0-255, K: 256-511)
    int head = (c & 255) >> 5, d = c & 31;
    f16* dst = (c < 256) ? Qd : Kd;
#pragma unroll
    for (int r = 0; r < 4; ++r) {
      int m = m0 + wv * 16 + g * 4 + r;
      int bb = m >> 11, nn = m & 2047;
      dst[(((size_t)bb * 8 + head) * 2048 + nn) * 32 + d] = (f16)acc[n4][r];
    }
  }
}

// ---------------- K2: fused dual-score flash attention (q-split, wpe=4) -----
// Grid 64x8x2 = 1024 blocks, 32 q-rows each. R14-proven structure; the ONLY
// change vs R14 is __launch_bounds__(256,4): R5 evidence says the 2nd arg,
// not resources, governs achieved residency (R5 (256,4)+1024blk -> 3 blk/CU;
// R14 (256,2)+1024blk -> stuck at 2 despite VGPR 88/LDS 30.7KB headroom).
// Waves 0-1: score stripes (16 rows each) + softmax -> PL. All 4 waves: PV
// for 32 q-rows x own 64-dd slice, lagged one tile. Work parity with the
// 512-block version. attn0 embedded in qt==0 blocks.
__global__ __launch_bounds__(256, 4) void k_flash(const f16* __restrict__ Qs,
    const f16* __restrict__ Ks, const f16* __restrict__ Qa,
    const f16* __restrict__ Ka, const f16* __restrict__ xt,
    float* __restrict__ out, float* __restrict__ out_cls,
    float* __restrict__ attn0) {
  __shared__ f16 KaL[2][64][40];     // pitch 80B
  __shared__ f16 KsL[2][64][40];
  __shared__ f16 PL[2][32][72];      // [q 0..31][j], pitch 144B
  __shared__ float alphaL[2][32] __attribute__((aligned(16)));
  __shared__ int   rsF[2][2] __attribute__((aligned(8)));
  __shared__ float lL[32];
  __shared__ float mHist[32];        // qt==0 only: per-tile m snapshot (raw)
  __shared__ float mFinS;
  int qt = blockIdx.x, h = blockIdx.y, b = blockIdx.z;
  int bh = b * 8 + h;
  int t = threadIdx.x, wv = t >> 6, ln = t & 63, cl = ln & 15, g = ln >> 4;
  bool isScore = wv < 2;
  bool isA0 = (qt == 0) && (wv == 0);    // wave holding q-row 0 scores
  float* a0base = attn0 + (size_t)b * 16384 + h * 2048;
  f32x4 z4 = {0.f, 0.f, 0.f, 0.f};

  // score-wave state (waves 0-1 only)
  f16x8 qsf = {}, qaf = {};
  if (isScore) {
    int qrow0 = qt * 32 + wv * 16;
    qsf = *(const f16x8*)&Qs[((size_t)bh * 2048 + qrow0 + cl) * 32 + g * 8];
    qaf = *(const f16x8*)&Qa[((size_t)bh * 2048 + qrow0 + cl) * 32 + g * 8];
  }
  f32x4 acc[2][4];                   // [qt2][ddt]; 32 q-rows x 64-dd slice
#pragma unroll
  for (int i = 0; i < 2; ++i)
#pragma unroll
    for (int j = 0; j < 4; ++j) acc[i][j] = z4;
  float m_run = -3.0e38f, l_lane = 0.f;  // raw-domain max; per-lane l partial
  int krow = t >> 2, koff = (t & 3) * 8;
  const f16* kaSrc = Ka + ((size_t)bh * 2048 + krow) * 32 + koff;
  const f16* ksSrc = Ks + ((size_t)bh * 2048 + krow) * 32 + koff;
  const f16* xb = xt + ((size_t)b * 256 + wv * 64) * 2048;

  float tv[16];                      // raw dual scores (score waves)
  f16x8 xf[2][4];                    // Xt B-frags for the lagged PV tile

  auto SCORE_MM = [&](int buf) {
#pragma unroll
    for (int jt = 0; jt < 4; ++jt) {
      f16x8 kaf = *(const f16x8*)&KaL[buf][jt * 16 + cl][g * 8];
      f16x8 ksf = *(const f16x8*)&KsL[buf][jt * 16 + cl][g * 8];
      f32x4 za = __builtin_amdgcn_mfma_f32_16x16x32_f16(kaf, qaf, z4, 0, 0, 0);
      f32x4 zs = __builtin_amdgcn_mfma_f32_16x16x32_f16(ksf, qsf, z4, 0, 0, 0);
#pragma unroll
      for (int r = 0; r < 4; ++r) tv[jt * 4 + r] = za[r] * zs[r];
    }
  };

  auto SCORE_FIN = [&](int buf, int kt) {
    float a0 = fmaxf(tv[0], tv[1]),   a1 = fmaxf(tv[2], tv[3]);
    float a2 = fmaxf(tv[4], tv[5]),   a3 = fmaxf(tv[6], tv[7]);
    float a4 = fmaxf(tv[8], tv[9]),   a5 = fmaxf(tv[10], tv[11]);
    float a6 = fmaxf(tv[12], tv[13]), a7 = fmaxf(tv[14], tv[15]);
    float b0 = fmaxf(a0, a1), b1 = fmaxf(a2, a3);
    float b2 = fmaxf(a4, a5), b3 = fmaxf(a6, a7);
    float lmax = fmaxf(fmaxf(b0, b1), fmaxf(b2, b3));
    int wflag = 0;
    if (__any(lmax > m_run + TH_RAW)) {      // rare: real max growth
      float tm = fmaxf(lmax, __shfl_xor(lmax, 16, 64));
      tm = fmaxf(tm, __shfl_xor(tm, 32, 64));
      float m_new = fmaxf(m_run, tm);
      float alpha = exp2f((m_run - m_new) * SCL);
      l_lane *= alpha;
      m_run = m_new;
      if (g == 0) alphaL[buf][wv * 16 + cl] = alpha;
      wflag = 1;
    }
    float mS = m_run * SCL;
    float p[16];
#pragma unroll
    for (int i = 0; i < 16; ++i) p[i] = exp2f(fmaf(tv[i], SCL, -mS));
    float s0 = p[0] + p[1],   s1 = p[2] + p[3];
    float s2 = p[4] + p[5],   s3 = p[6] + p[7];
    float s4 = p[8] + p[9],   s5 = p[10] + p[11];
    float s6 = p[12] + p[13], s7 = p[14] + p[15];
    float u0 = s0 + s1, u1 = s2 + s3, u2 = s4 + s5, u3 = s6 + s7;
    l_lane += (u0 + u1) + (u2 + u3);         // per-lane partial; reduce at end
#pragma unroll
    for (int jt = 0; jt < 4; ++jt) {
      auto lo = __builtin_amdgcn_cvt_pkrtz(p[jt * 4 + 0], p[jt * 4 + 1]);
      auto hi = __builtin_amdgcn_cvt_pkrtz(p[jt * 4 + 2], p[jt * 4 + 3]);
      f16x4 pk = { (f16)lo[0], (f16)lo[1], (f16)hi[0], (f16)hi[1] };
      *(f16x4*)&PL[buf][wv * 16 + cl][jt * 16 + g * 4] = pk;
    }
    if (ln == 0) rsF[buf][wv] = wflag;
    // attn0 embed: wave 0 of qt==0 blocks, lanes cl==0 hold P[0][j]
    if (isA0) {
      if (ln == 0) mHist[kt] = m_run;
      if (cl == 0) {
#pragma unroll
        for (int jt = 0; jt < 4; ++jt) {
          float4 pw = { p[jt * 4 + 0], p[jt * 4 + 1],
                        p[jt * 4 + 2], p[jt * 4 + 3] };
          *(float4*)(a0base + kt * 64 + jt * 16 + g * 4) = pw;
        }
      }
    }
  };

  auto XFLOAD = [&](int kt) {
#pragma unroll
    for (int ks2 = 0; ks2 < 2; ++ks2)
#pragma unroll
      for (int ddt = 0; ddt < 4; ++ddt)
        xf[ks2][ddt] = *(const f16x8*)(xb + (size_t)(ddt * 16 + cl) * 2048 +
                                       kt * 64 + ks2 * 32 + g * 8);
  };

  auto PVDO = [&](int pbuf) {
    int flq0 = rsF[pbuf][0], flq1 = rsF[pbuf][1];
    int flq[2] = { flq0, flq1 };
#pragma unroll
    for (int qt2 = 0; qt2 < 2; ++qt2) {
      if (flq[qt2]) {
        f32x4 a4 = *(const f32x4*)&alphaL[pbuf][qt2 * 16 + g * 4];
#pragma unroll
        for (int ddt = 0; ddt < 4; ++ddt)
#pragma unroll
          for (int r = 0; r < 4; ++r) acc[qt2][ddt][r] *= a4[r];
      }
    }
#pragma unroll
    for (int ks2 = 0; ks2 < 2; ++ks2) {
      f16x8 pf[2];
#pragma unroll
      for (int qt2 = 0; qt2 < 2; ++qt2)
        pf[qt2] = *(const f16x8*)&PL[pbuf][qt2 * 16 + cl][ks2 * 32 + g * 8];
#pragma unroll
      for (int ddt = 0; ddt < 4; ++ddt)
#pragma unroll
        for (int qt2 = 0; qt2 < 2; ++qt2)
          acc[qt2][ddt] = __builtin_amdgcn_mfma_f32_16x16x32_f16(
              pf[qt2], xf[ks2][ddt], acc[qt2][ddt], 0, 0, 0);
    }
  };

  // ---- prologue: stage K tile 0 (all 256 threads) ----
  *(f16x8*)&KaL[0][krow][koff] = *(const f16x8*)kaSrc;
  *(f16x8*)&KsL[0][krow][koff] = *(const f16x8*)ksSrc;
  __syncthreads();

  // I_0: score(0) only; commit K(1)
  f16x8 kan = *(const f16x8*)(kaSrc + 2048);
  f16x8 ksn = *(const f16x8*)(ksSrc + 2048);
  if (isScore) {
    SCORE_MM(0);
    SCORE_FIN(0, 0);
  }
  *(f16x8*)&KaL[1][krow][koff] = kan;
  *(f16x8*)&KsL[1][krow][koff] = ksn;
  __syncthreads();

  // main loop: interval k = score(k) [waves 0-1] + PV(k-1) [all waves]
  for (int k = 1; k < 32; ++k) {
    int sbuf = k & 1, pbuf = sbuf ^ 1;
    XFLOAD(k - 1);                           // global loads in flight early
    if (k < 31) {
      kan = *(const f16x8*)(kaSrc + (size_t)(k + 1) * 2048);
      ksn = *(const f16x8*)(ksSrc + (size_t)(k + 1) * 2048);
    }
    if (isScore) SCORE_MM(sbuf);             // 8 MFMA (heavy waves)
    PVDO(pbuf);                              // 16 MFMA (all waves)
    if (isScore) SCORE_FIN(sbuf, k);         // softmax overlaps pipe drain
    if (k < 31) {
      *(f16x8*)&KaL[pbuf][krow][koff] = kan;
      *(f16x8*)&KsL[pbuf][krow][koff] = ksn;
    }
    __syncthreads();
  }

  // drain: PV tile 31 (PL buffer 1)
  XFLOAD(31);
  PVDO(1);

  // l reduction (deferred): score waves only
  if (isScore) {
    l_lane += __shfl_xor(l_lane, 16, 64);
    l_lane += __shfl_xor(l_lane, 32, 64);
    if (g == 0) lL[wv * 16 + cl] = l_lane;
  }
  if (isA0 && ln == 0) mFinS = m_run;        // row-0 final max (raw domain)
  __syncthreads();
#pragma unroll
  for (int qt2 = 0; qt2 < 2; ++qt2) {
#pragma unroll
    for (int r = 0; r < 4; ++r) {
      float linv = 1.0f / lL[qt2 * 16 + g * 4 + r];
      int q = qt * 32 + qt2 * 16 + g * 4 + r;
#pragma unroll
      for (int ddt = 0; ddt < 4; ++ddt) {
        float v = acc[qt2][ddt][r] * linv;
        int col = h * 256 + wv * 64 + ddt * 16 + cl;
        out[((size_t)b * 2048 + q) * 2048 + col] = v;
        if (q == 0) out_cls[(size_t)b * 2048 + col] = v;
      }
    }
  }
  // attn0 fix-up: rescale raw p by 2^((m_tile-m_fin)*SCL)/l0, in place
  if (qt == 0) {
    float l0inv = 1.0f / lL[0];
    float mf = mFinS;
    for (int i = t; i < 2048; i += 256) {
      float v = a0base[i];
      a0base[i] = v * exp2f((mHist[i >> 6] - mf) * SCL) * l0inv;
    }
  }
}

extern "C" void kernel_launch(void* const* d_in, const int* in_sizes, int n_in,
                              void* d_out, int out_size, void* d_ws, size_t ws_size,
                              hipStream_t stream) {
  const float* x  = (const float*)d_in[0];
  const float* af = (const float*)d_in[1];
  const float* Wq = (const float*)d_in[2];
  const float* Wa = (const float*)d_in[3];
  // ws (f16): Qs|Ks|Qa|Ka (4x1M) | xt (1M) | Wt (256K)  ~= 10.5 MB
  const size_t QK = (size_t)2 * 8 * 2048 * 32;
  f16* Qs = (f16*)d_ws;
  f16* Ks = Qs + QK;
  f16* Qa = Ks + QK;
  f16* Ka = Qa + QK;
  f16* xt = Ka + QK;
  f16* Wt = xt + QK;
  float* out     = (float*)d_out;
  float* out_cls = out + (size_t)2 * 2048 * 2048;
  float* attn0   = out_cls + 2 * 2048;

  k_W<<<dim3(8, 4, 2), 256, 0, stream>>>(Wq, Wa, Wt);
  k_proj<<<dim3(80, 8, 2), 256, 0, stream>>>(x, af, Wt, Qs, Ks, Qa, Ka, xt);
  k_flash<<<dim3(64, 8, 2), 256, 0, stream>>>(Qs, Ks, Qa, Ka, xt, out, out_cls,
                                              attn0);
}

// Round 17
// 175.316 us; speedup vs baseline: 1.5507x; 1.5507x over previous
//
#include <hip/hip_runtime.h>

typedef _Float16 f16;
typedef _Float16 f16x4 __attribute__((ext_vector_type(4)));
typedef _Float16 f16x8 __attribute__((ext_vector_type(8)));
typedef float f32x4 __attribute__((ext_vector_type(4)));

#define LOG2E 1.4426950408889634f
#define SCL   (1.4426950408889634f / 32.0f)   // SCALE^2 * log2(e) folded
#define TH_RAW 177.445f                        // 8.0 / SCL : defer-max threshold

// ---------------- K0: W[s][256][768] f32 -> Wt[s][512][256] f16 (Q|K cols) --
__global__ __launch_bounds__(256) void k_W(const float* __restrict__ Wq,
    const float* __restrict__ Wa, f16* __restrict__ Wt) {
  __shared__ f16 tile[64][65];
  int n0 = blockIdx.x * 64, k0 = blockIdx.y * 64, s = blockIdx.z;
  const float* W = s ? Wa : Wq;
  f16* dst = Wt + (size_t)s * 512 * 256;
  int t = threadIdx.x, c = t & 63, rg = t >> 6;
#pragma unroll
  for (int r = 0; r < 16; ++r) {
    int krow = r * 4 + rg;
    tile[krow][c] = (f16)W[(size_t)(k0 + krow) * 768 + n0 + c];
  }
  __syncthreads();
#pragma unroll
  for (int r = 0; r < 16; ++r) {
    int nrow = r * 4 + rg;
    dst[(size_t)(n0 + nrow) * 256 + k0 + c] = tile[c][nrow];
  }
}

// ---------------- K1: Q/K projections + x-transpose riders -------------------
// bx<64: proj block (mt=bx, nt=by, s=bz). Out Q*/K* as [b*8+h][2048][32] f16.
// bx>=64: x-transpose rider: x[b][2048][256] f32 -> xt[b][256][2048] f16.
__global__ __launch_bounds__(256) void k_proj(const float* __restrict__ x,
    const float* __restrict__ af, const f16* __restrict__ Wt,
    f16* __restrict__ Qs, f16* __restrict__ Ks,
    f16* __restrict__ Qa, f16* __restrict__ Ka, f16* __restrict__ xt) {
  __shared__ f16 tile[64][65];
  int t = threadIdx.x;
  if (blockIdx.x >= 64) {
    // ---- x-transpose rider ----
    int r = ((blockIdx.z * 8 + blockIdx.y) * 16 + (blockIdx.x - 64));
    int n0 = (r & 31) * 64, d0 = ((r >> 5) & 3) * 64, b = r >> 7;
    int c = t & 63, rg = t >> 6;
#pragma unroll
    for (int rr = 0; rr < 16; ++rr) {
      int row = rr * 4 + rg;
      tile[row][c] = (f16)x[((size_t)b * 2048 + n0 + row) * 256 + d0 + c];
    }
    __syncthreads();
#pragma unroll
    for (int rr = 0; rr < 16; ++rr) {
      int drow = rr * 4 + rg;
      xt[((size_t)b * 256 + d0 + drow) * 2048 + n0 + c] = tile[c][drow];
    }
    return;
  }
  int mt = blockIdx.x, nt = blockIdx.y, s = blockIdx.z;
  const float* A = s ? af : x;
  const f16* W = Wt + (size_t)s * 512 * 256;
  f16* Qd = s ? Qa : Qs;
  f16* Kd = s ? Ka : Ks;
  int wv = t >> 6, ln = t & 63, cl = ln & 15, g = ln >> 4;
  int m0 = mt * 64, n0 = nt * 64;
  const float* arow = A + (size_t)(m0 + wv * 16 + cl) * 256 + g * 8;
  const f16* wb = W + (size_t)n0 * 256 + g * 8;
  f32x4 z4 = {0.f, 0.f, 0.f, 0.f};
  f32x4 acc[4] = {z4, z4, z4, z4};
#pragma unroll
  for (int k32 = 0; k32 < 8; ++k32) {
    float4 u = *(const float4*)(arow + k32 * 32);
    float4 v = *(const float4*)(arow + k32 * 32 + 4);
    f16x8 a = { (f16)u.x, (f16)u.y, (f16)u.z, (f16)u.w,
                (f16)v.x, (f16)v.y, (f16)v.z, (f16)v.w };
#pragma unroll
    for (int n4 = 0; n4 < 4; ++n4) {
      f16x8 bf = *(const f16x8*)(wb + (size_t)(n4 * 16 + cl) * 256 + k32 * 32);
      acc[n4] = __builtin_amdgcn_mfma_f32_16x16x32_f16(a, bf, acc[n4], 0, 0, 0);
    }
  }
#pragma unroll
  for (int n4 = 0; n4 < 4; ++n4) {
    int c = n0 + n4 * 16 + cl;               // 0..511 (Q: 0-255, K: 256-511)
    int head = (c & 255) >> 5, d = c & 31;
    f16* dst = (c < 256) ? Qd : Kd;
#pragma unroll
    for (int r = 0; r < 4; ++r) {
      int m = m0 + wv * 16 + g * 4 + r;
      int bb = m >> 11, nn = m & 2047;
      dst[(((size_t)bb * 8 + head) * 2048 + nn) * 32 + d] = (f16)acc[n4][r];
    }
  }
}

// ---------------- K2: fused dual-score flash attention ----------------------
// Grid exactly 32x8x2 = 512 blocks (2 full CU rounds, no partial tail).
// R2-proven loop (81us): 4 waves, 64 q-rows, KV tile 64, K dbuf LDS, Xt from
// L2, zero-shuffle defer-max, deferred l-reduction.
// attn0 (row-0 probs) EMBEDDED in qt==0 blocks: wave 0 lanes cl==0 hold
// P[0][j] each tile -> store raw p + per-tile max history; epilogue rescales
// in place by 2^((m_tile-m_fin)*SCL)/l0. No rider blocks, no extra launch.
__global__ __launch_bounds__(256, 2) void k_flash(const f16* __restrict__ Qs,
    const f16* __restrict__ Ks, const f16* __restrict__ Qa,
    const f16* __restrict__ Ka, const f16* __restrict__ xt,
    float* __restrict__ out, float* __restrict__ out_cls,
    float* __restrict__ attn0) {
  __shared__ f16 KaL[2][64][40];     // pitch 80B
  __shared__ f16 KsL[2][64][40];
  __shared__ f16 PL[2][64][72];      // [q][j], pitch 144B
  __shared__ float alphaL[2][64] __attribute__((aligned(16)));
  __shared__ int   rsF[2][4] __attribute__((aligned(16)));
  __shared__ float lL[64];
  __shared__ float mHist[32];        // qt==0 only: per-tile m snapshot (raw)
  __shared__ float mFinS;
  int qt = blockIdx.x, h = blockIdx.y, b = blockIdx.z;
  int bh = b * 8 + h;
  int t = threadIdx.x, wv = t >> 6, ln = t & 63, cl = ln & 15, g = ln >> 4;
  bool isA0 = (qt == 0) && (wv == 0);    // wave holding q-row 0 scores
  float* a0base = attn0 + (size_t)b * 16384 + h * 2048;
  int qrow0 = qt * 64 + wv * 16;
  f16x8 qsf = *(const f16x8*)&Qs[((size_t)bh * 2048 + qrow0 + cl) * 32 + g * 8];
  f16x8 qaf = *(const f16x8*)&Qa[((size_t)bh * 2048 + qrow0 + cl) * 32 + g * 8];
  f32x4 z4 = {0.f, 0.f, 0.f, 0.f};
  f32x4 acc[4][4];                   // [qt2][ddt]; D rows=q (g*4+r), cols=dd (cl)
#pragma unroll
  for (int i = 0; i < 4; ++i)
#pragma unroll
    for (int j = 0; j < 4; ++j) acc[i][j] = z4;
  float m_run = -3.0e38f, l_lane = 0.f;  // raw-domain max; per-lane l partial
  int krow = t >> 2, koff = (t & 3) * 8;
  const f16* kaSrc = Ka + ((size_t)bh * 2048 + krow) * 32 + koff;
  const f16* ksSrc = Ks + ((size_t)bh * 2048 + krow) * 32 + koff;
  const f16* xb = xt + ((size_t)b * 256 + wv * 64) * 2048;

  float tv[16];                      // raw dual scores for current tile
  f16x8 xf[2][4];                    // Xt B-frags for the lagged PV tile

  // ---- score MFMAs from KL[buf] -> tv (raw domain) ----
  auto SCORE_MM = [&](int buf) {
#pragma unroll
    for (int jt = 0; jt < 4; ++jt) {
      f16x8 kaf = *(const f16x8*)&KaL[buf][jt * 16 + cl][g * 8];
      f16x8 ksf = *(const f16x8*)&KsL[buf][jt * 16 + cl][g * 8];
      f32x4 za = __builtin_amdgcn_mfma_f32_16x16x32_f16(kaf, qaf, z4, 0, 0, 0);
      f32x4 zs = __builtin_amdgcn_mfma_f32_16x16x32_f16(ksf, qsf, z4, 0, 0, 0);
#pragma unroll
      for (int r = 0; r < 4; ++r) tv[jt * 4 + r] = za[r] * zs[r];
    }
  };

  // ---- softmax finish; zero-shuffle common path; deferred l-reduction.
  //      kt: tile index, used only by the qt==0 attn0 embed. ----
  auto SCORE_FIN = [&](int buf, int kt) {
    float a0 = fmaxf(tv[0], tv[1]),   a1 = fmaxf(tv[2], tv[3]);
    float a2 = fmaxf(tv[4], tv[5]),   a3 = fmaxf(tv[6], tv[7]);
    float a4 = fmaxf(tv[8], tv[9]),   a5 = fmaxf(tv[10], tv[11]);
    float a6 = fmaxf(tv[12], tv[13]), a7 = fmaxf(tv[14], tv[15]);
    float b0 = fmaxf(a0, a1), b1 = fmaxf(a2, a3);
    float b2 = fmaxf(a4, a5), b3 = fmaxf(a6, a7);
    float lmax = fmaxf(fmaxf(b0, b1), fmaxf(b2, b3));
    int wflag = 0;
    if (__any(lmax > m_run + TH_RAW)) {      // rare: real max growth
      float tm = fmaxf(lmax, __shfl_xor(lmax, 16, 64));
      tm = fmaxf(tm, __shfl_xor(tm, 32, 64));
      float m_new = fmaxf(m_run, tm);
      float alpha = exp2f((m_run - m_new) * SCL);
      l_lane *= alpha;
      m_run = m_new;
      if (g == 0) alphaL[buf][wv * 16 + cl] = alpha;
      wflag = 1;
    }
    float mS = m_run * SCL;
    float p[16];
#pragma unroll
    for (int i = 0; i < 16; ++i) p[i] = exp2f(fmaf(tv[i], SCL, -mS));
    float s0 = p[0] + p[1],   s1 = p[2] + p[3];
    float s2 = p[4] + p[5],   s3 = p[6] + p[7];
    float s4 = p[8] + p[9],   s5 = p[10] + p[11];
    float s6 = p[12] + p[13], s7 = p[14] + p[15];
    float u0 = s0 + s1, u1 = s2 + s3, u2 = s4 + s5, u3 = s6 + s7;
    l_lane += (u0 + u1) + (u2 + u3);         // per-lane partial; reduce at end
#pragma unroll
    for (int jt = 0; jt < 4; ++jt) {
      auto lo = __builtin_amdgcn_cvt_pkrtz(p[jt * 4 + 0], p[jt * 4 + 1]);
      auto hi = __builtin_amdgcn_cvt_pkrtz(p[jt * 4 + 2], p[jt * 4 + 3]);
      f16x4 pk = { (f16)lo[0], (f16)lo[1], (f16)hi[0], (f16)hi[1] };
      *(f16x4*)&PL[buf][wv * 16 + cl][jt * 16 + g * 4] = pk;
    }
    if (ln == 0) rsF[buf][wv] = wflag;
    // attn0 embed: wave 0 of qt==0 blocks, lanes cl==0 hold P[0][j]
    if (isA0) {
      if (ln == 0) mHist[kt] = m_run;
      if (cl == 0) {
#pragma unroll
        for (int jt = 0; jt < 4; ++jt) {
          float4 pw = { p[jt * 4 + 0], p[jt * 4 + 1],
                        p[jt * 4 + 2], p[jt * 4 + 3] };
          *(float4*)(a0base + kt * 64 + jt * 16 + g * 4) = pw;
        }
      }
    }
  };

  // ---- Xt B-frag loads for PV tile kt ----
  auto XFLOAD = [&](int kt) {
#pragma unroll
    for (int ks2 = 0; ks2 < 2; ++ks2)
#pragma unroll
      for (int ddt = 0; ddt < 4; ++ddt)
        xf[ks2][ddt] = *(const f16x8*)(xb + (size_t)(ddt * 16 + cl) * 2048 +
                                       kt * 64 + ks2 * 32 + g * 8);
  };

  // ---- PV for PL[pbuf] (lagged tile), with gated rescale ----
  auto PVDO = [&](int pbuf) {
    int4 fl = *(const int4*)&rsF[pbuf][0];
    int flq[4] = { fl.x, fl.y, fl.z, fl.w };
#pragma unroll
    for (int qt2 = 0; qt2 < 4; ++qt2) {
      if (flq[qt2]) {
        f32x4 a4 = *(const f32x4*)&alphaL[pbuf][qt2 * 16 + g * 4];
#pragma unroll
        for (int ddt = 0; ddt < 4; ++ddt)
#pragma unroll
          for (int r = 0; r < 4; ++r) acc[qt2][ddt][r] *= a4[r];
      }
    }
#pragma unroll
    for (int ks2 = 0; ks2 < 2; ++ks2) {
      f16x8 pf[4];
#pragma unroll
      for (int qt2 = 0; qt2 < 4; ++qt2)
        pf[qt2] = *(const f16x8*)&PL[pbuf][qt2 * 16 + cl][ks2 * 32 + g * 8];
#pragma unroll
      for (int ddt = 0; ddt < 4; ++ddt)
#pragma unroll
        for (int qt2 = 0; qt2 < 4; ++qt2)
          acc[qt2][ddt] = __builtin_amdgcn_mfma_f32_16x16x32_f16(
              pf[qt2], xf[ks2][ddt], acc[qt2][ddt], 0, 0, 0);
    }
  };

  // ---- prologue: stage K tile 0 ----
  *(f16x8*)&KaL[0][krow][koff] = *(const f16x8*)kaSrc;
  *(f16x8*)&KsL[0][krow][koff] = *(const f16x8*)ksSrc;
  __syncthreads();

  // I_0: score(0) only; commit K(1)
  f16x8 kan = *(const f16x8*)(kaSrc + 2048);
  f16x8 ksn = *(const f16x8*)(ksSrc + 2048);
  SCORE_MM(0);
  SCORE_FIN(0, 0);
  *(f16x8*)&KaL[1][krow][koff] = kan;
  *(f16x8*)&KsL[1][krow][koff] = ksn;
  __syncthreads();

  // main loop: interval k = score(k) + PV(k-1)
  for (int k = 1; k < 32; ++k) {
    int sbuf = k & 1, pbuf = sbuf ^ 1;
    XFLOAD(k - 1);                           // global loads in flight early
    if (k < 31) {
      kan = *(const f16x8*)(kaSrc + (size_t)(k + 1) * 2048);
      ksn = *(const f16x8*)(ksSrc + (size_t)(k + 1) * 2048);
    }
    SCORE_MM(sbuf);                          // 8 MFMA (current tile)
    PVDO(pbuf);                              // 32 MFMA (lagged tile)
    SCORE_FIN(sbuf, k);                      // softmax VALU overlaps pipe drain
    if (k < 31) {
      *(f16x8*)&KaL[pbuf][krow][koff] = kan;
      *(f16x8*)&KsL[pbuf][krow][koff] = ksn;
    }
    __syncthreads();
  }

  // drain: PV tile 31 (PL buffer 1)
  XFLOAD(31);
  PVDO(1);

  // l reduction (deferred): once per kernel instead of per tile
  l_lane += __shfl_xor(l_lane, 16, 64);
  l_lane += __shfl_xor(l_lane, 32, 64);
  if (g == 0) lL[wv * 16 + cl] = l_lane;
  if (isA0 && ln == 0) mFinS = m_run;        // row-0 final max (raw domain)
  __syncthreads();
#pragma unroll
  for (int qt2 = 0; qt2 < 4; ++qt2) {
#pragma unroll
    for (int r = 0; r < 4; ++r) {
      float linv = 1.0f / lL[qt2 * 16 + g * 4 + r];
      int q = qt * 64 + qt2 * 16 + g * 4 + r;
#pragma unroll
      for (int ddt = 0; ddt < 4; ++ddt) {
        float v = acc[qt2][ddt][r] * linv;
        int col = h * 256 + wv * 64 + ddt * 16 + cl;
        out[((size_t)b * 2048 + q) * 2048 + col] = v;
        if (q == 0) out_cls[(size_t)b * 2048 + col] = v;
      }
    }
  }
  // attn0 fix-up: rescale raw p by 2^((m_tile-m_fin)*SCL)/l0, in place
  if (qt == 0) {
    float l0inv = 1.0f / lL[0];
    float mf = mFinS;
    for (int i = t; i < 2048; i += 256) {
      float v = a0base[i];
      a0base[i] = v * exp2f((mHist[i >> 6] - mf) * SCL) * l0inv;
    }
  }
}

extern "C" void kernel_launch(void* const* d_in, const int* in_sizes, int n_in,
                              void* d_out, int out_size, void* d_ws, size_t ws_size,
                              hipStream_t stream) {
  const float* x  = (const float*)d_in[0];
  const float* af = (const float*)d_in[1];
  const float* Wq = (const float*)d_in[2];
  const float* Wa = (const float*)d_in[3];
  // ws (f16): Qs|Ks|Qa|Ka (4x1M) | xt (1M) | Wt (256K)  ~= 10.5 MB
  const size_t QK = (size_t)2 * 8 * 2048 * 32;
  f16* Qs = (f16*)d_ws;
  f16* Ks = Qs + QK;
  f16* Qa = Ks + QK;
  f16* Ka = Qa + QK;
  f16* xt = Ka + QK;
  f16* Wt = xt + QK;
  float* out     = (float*)d_out;
  float* out_cls = out + (size_t)2 * 2048 * 2048;
  float* attn0   = out_cls + 2 * 2048;

  k_W<<<dim3(8, 4, 2), 256, 0, stream>>>(Wq, Wa, Wt);
  k_proj<<<dim3(80, 8, 2), 256, 0, stream>>>(x, af, Wt, Qs, Ks, Qa, Ka, xt);
  k_flash<<<dim3(32, 8, 2), 256, 0, stream>>>(Qs, Ks, Qa, Ka, xt, out, out_cls,
                                              attn0);
}

// Round 18
// 171.768 us; speedup vs baseline: 1.5827x; 1.0207x over previous
//
#include <hip/hip_runtime.h>

typedef _Float16 f16;
typedef _Float16 f16x4 __attribute__((ext_vector_type(4)));
typedef _Float16 f16x8 __attribute__((ext_vector_type(8)));
typedef float f32x4 __attribute__((ext_vector_type(4)));

#define LOG2E 1.4426950408889634f
#define SCL   (1.4426950408889634f / 32.0f)   // SCALE^2 * log2(e) folded
#define TH_RAW 177.445f                        // 8.0 / SCL : defer-max threshold

// ---------------- K0: W[s][256][768] f32 -> Wt[s][512][256] f16 (Q|K cols) --
__global__ __launch_bounds__(256) void k_W(const float* __restrict__ Wq,
    const float* __restrict__ Wa, f16* __restrict__ Wt) {
  __shared__ f16 tile[64][65];
  int n0 = blockIdx.x * 64, k0 = blockIdx.y * 64, s = blockIdx.z;
  const float* W = s ? Wa : Wq;
  f16* dst = Wt + (size_t)s * 512 * 256;
  int t = threadIdx.x, c = t & 63, rg = t >> 6;
#pragma unroll
  for (int r = 0; r < 16; ++r) {
    int krow = r * 4 + rg;
    tile[krow][c] = (f16)W[(size_t)(k0 + krow) * 768 + n0 + c];
  }
  __syncthreads();
#pragma unroll
  for (int r = 0; r < 16; ++r) {
    int nrow = r * 4 + rg;
    dst[(size_t)(n0 + nrow) * 256 + k0 + c] = tile[c][nrow];
  }
}

// ---------------- K1: Q/K projections + x-transpose riders -------------------
// bx<64: proj block (mt=bx, nt=by, s=bz). Out Q*/K* as [b*8+h][2048][32] f16.
// bx>=64: x-transpose rider: x[b][2048][256] f32 -> xt[b][256][2048] f16.
__global__ __launch_bounds__(256) void k_proj(const float* __restrict__ x,
    const float* __restrict__ af, const f16* __restrict__ Wt,
    f16* __restrict__ Qs, f16* __restrict__ Ks,
    f16* __restrict__ Qa, f16* __restrict__ Ka, f16* __restrict__ xt) {
  __shared__ f16 tile[64][65];
  int t = threadIdx.x;
  if (blockIdx.x >= 64) {
    // ---- x-transpose rider ----
    int r = ((blockIdx.z * 8 + blockIdx.y) * 16 + (blockIdx.x - 64));
    int n0 = (r & 31) * 64, d0 = ((r >> 5) & 3) * 64, b = r >> 7;
    int c = t & 63, rg = t >> 6;
#pragma unroll
    for (int rr = 0; rr < 16; ++rr) {
      int row = rr * 4 + rg;
      tile[row][c] = (f16)x[((size_t)b * 2048 + n0 + row) * 256 + d0 + c];
    }
    __syncthreads();
#pragma unroll
    for (int rr = 0; rr < 16; ++rr) {
      int drow = rr * 4 + rg;
      xt[((size_t)b * 256 + d0 + drow) * 2048 + n0 + c] = tile[c][drow];
    }
    return;
  }
  int mt = blockIdx.x, nt = blockIdx.y, s = blockIdx.z;
  const float* A = s ? af : x;
  const f16* W = Wt + (size_t)s * 512 * 256;
  f16* Qd = s ? Qa : Qs;
  f16* Kd = s ? Ka : Ks;
  int wv = t >> 6, ln = t & 63, cl = ln & 15, g = ln >> 4;
  int m0 = mt * 64, n0 = nt * 64;
  const float* arow = A + (size_t)(m0 + wv * 16 + cl) * 256 + g * 8;
  const f16* wb = W + (size_t)n0 * 256 + g * 8;
  f32x4 z4 = {0.f, 0.f, 0.f, 0.f};
  f32x4 acc[4] = {z4, z4, z4, z4};
#pragma unroll
  for (int k32 = 0; k32 < 8; ++k32) {
    float4 u = *(const float4*)(arow + k32 * 32);
    float4 v = *(const float4*)(arow + k32 * 32 + 4);
    f16x8 a = { (f16)u.x, (f16)u.y, (f16)u.z, (f16)u.w,
                (f16)v.x, (f16)v.y, (f16)v.z, (f16)v.w };
#pragma unroll
    for (int n4 = 0; n4 < 4; ++n4) {
      f16x8 bf = *(const f16x8*)(wb + (size_t)(n4 * 16 + cl) * 256 + k32 * 32);
      acc[n4] = __builtin_amdgcn_mfma_f32_16x16x32_f16(a, bf, acc[n4], 0, 0, 0);
    }
  }
#pragma unroll
  for (int n4 = 0; n4 < 4; ++n4) {
    int c = n0 + n4 * 16 + cl;               // 0..511 (Q: 0-255, K: 256-511)
    int head = (c & 255) >> 5, d = c & 31;
    f16* dst = (c < 256) ? Qd : Kd;
#pragma unroll
    for (int r = 0; r < 4; ++r) {
      int m = m0 + wv * 16 + g * 4 + r;
      int bb = m >> 11, nn = m & 2047;
      dst[(((size_t)bb * 8 + head) * 2048 + nn) * 32 + d] = (f16)acc[n4][r];
    }
  }
}

// ---------------- K2: fused dual-score flash attention ----------------------
// Grid exactly 32x8x2 = 512 blocks (2 full CU rounds, no partial tail).
// R2-proven loop: 4 waves, 64 q-rows, KV tile 64, K dbuf LDS, Xt from L2,
// zero-shuffle defer-max, deferred l-reduction, attn0 embedded in qt==0.
// NEW (T5): s_setprio(1) around the 40-MFMA cluster. Mechanism: 2 INDEPENDENT
// blocks share each CU and drift out of phase; priority steers the scheduler
// toward the block currently issuing MFMAs over the other block's staging
// waves (guide m191: +4-7% for independent-block attn; null only for
// barrier-lockstep waves, m190 -- our cross-block case is the former).
__global__ __launch_bounds__(256, 2) void k_flash(const f16* __restrict__ Qs,
    const f16* __restrict__ Ks, const f16* __restrict__ Qa,
    const f16* __restrict__ Ka, const f16* __restrict__ xt,
    float* __restrict__ out, float* __restrict__ out_cls,
    float* __restrict__ attn0) {
  __shared__ f16 KaL[2][64][40];     // pitch 80B
  __shared__ f16 KsL[2][64][40];
  __shared__ f16 PL[2][64][72];      // [q][j], pitch 144B
  __shared__ float alphaL[2][64] __attribute__((aligned(16)));
  __shared__ int   rsF[2][4] __attribute__((aligned(16)));
  __shared__ float lL[64];
  __shared__ float mHist[32];        // qt==0 only: per-tile m snapshot (raw)
  __shared__ float mFinS;
  int qt = blockIdx.x, h = blockIdx.y, b = blockIdx.z;
  int bh = b * 8 + h;
  int t = threadIdx.x, wv = t >> 6, ln = t & 63, cl = ln & 15, g = ln >> 4;
  bool isA0 = (qt == 0) && (wv == 0);    // wave holding q-row 0 scores
  float* a0base = attn0 + (size_t)b * 16384 + h * 2048;
  int qrow0 = qt * 64 + wv * 16;
  f16x8 qsf = *(const f16x8*)&Qs[((size_t)bh * 2048 + qrow0 + cl) * 32 + g * 8];
  f16x8 qaf = *(const f16x8*)&Qa[((size_t)bh * 2048 + qrow0 + cl) * 32 + g * 8];
  f32x4 z4 = {0.f, 0.f, 0.f, 0.f};
  f32x4 acc[4][4];                   // [qt2][ddt]; D rows=q (g*4+r), cols=dd (cl)
#pragma unroll
  for (int i = 0; i < 4; ++i)
#pragma unroll
    for (int j = 0; j < 4; ++j) acc[i][j] = z4;
  float m_run = -3.0e38f, l_lane = 0.f;  // raw-domain max; per-lane l partial
  int krow = t >> 2, koff = (t & 3) * 8;
  const f16* kaSrc = Ka + ((size_t)bh * 2048 + krow) * 32 + koff;
  const f16* ksSrc = Ks + ((size_t)bh * 2048 + krow) * 32 + koff;
  const f16* xb = xt + ((size_t)b * 256 + wv * 64) * 2048;

  float tv[16];                      // raw dual scores for current tile
  f16x8 xf[2][4];                    // Xt B-frags for the lagged PV tile

  // ---- score MFMAs from KL[buf] -> tv (raw domain) ----
  auto SCORE_MM = [&](int buf) {
#pragma unroll
    for (int jt = 0; jt < 4; ++jt) {
      f16x8 kaf = *(const f16x8*)&KaL[buf][jt * 16 + cl][g * 8];
      f16x8 ksf = *(const f16x8*)&KsL[buf][jt * 16 + cl][g * 8];
      f32x4 za = __builtin_amdgcn_mfma_f32_16x16x32_f16(kaf, qaf, z4, 0, 0, 0);
      f32x4 zs = __builtin_amdgcn_mfma_f32_16x16x32_f16(ksf, qsf, z4, 0, 0, 0);
#pragma unroll
      for (int r = 0; r < 4; ++r) tv[jt * 4 + r] = za[r] * zs[r];
    }
  };

  // ---- softmax finish; zero-shuffle common path; deferred l-reduction.
  //      kt: tile index, used only by the qt==0 attn0 embed. ----
  auto SCORE_FIN = [&](int buf, int kt) {
    float a0 = fmaxf(tv[0], tv[1]),   a1 = fmaxf(tv[2], tv[3]);
    float a2 = fmaxf(tv[4], tv[5]),   a3 = fmaxf(tv[6], tv[7]);
    float a4 = fmaxf(tv[8], tv[9]),   a5 = fmaxf(tv[10], tv[11]);
    float a6 = fmaxf(tv[12], tv[13]), a7 = fmaxf(tv[14], tv[15]);
    float b0 = fmaxf(a0, a1), b1 = fmaxf(a2, a3);
    float b2 = fmaxf(a4, a5), b3 = fmaxf(a6, a7);
    float lmax = fmaxf(fmaxf(b0, b1), fmaxf(b2, b3));
    int wflag = 0;
    if (__any(lmax > m_run + TH_RAW)) {      // rare: real max growth
      float tm = fmaxf(lmax, __shfl_xor(lmax, 16, 64));
      tm = fmaxf(tm, __shfl_xor(tm, 32, 64));
      float m_new = fmaxf(m_run, tm);
      float alpha = exp2f((m_run - m_new) * SCL);
      l_lane *= alpha;
      m_run = m_new;
      if (g == 0) alphaL[buf][wv * 16 + cl] = alpha;
      wflag = 1;
    }
    float mS = m_run * SCL;
    float p[16];
#pragma unroll
    for (int i = 0; i < 16; ++i) p[i] = exp2f(fmaf(tv[i], SCL, -mS));
    float s0 = p[0] + p[1],   s1 = p[2] + p[3];
    float s2 = p[4] + p[5],   s3 = p[6] + p[7];
    float s4 = p[8] + p[9],   s5 = p[10] + p[11];
    float s6 = p[12] + p[13], s7 = p[14] + p[15];
    float u0 = s0 + s1, u1 = s2 + s3, u2 = s4 + s5, u3 = s6 + s7;
    l_lane += (u0 + u1) + (u2 + u3);         // per-lane partial; reduce at end
#pragma unroll
    for (int jt = 0; jt < 4; ++jt) {
      auto lo = __builtin_amdgcn_cvt_pkrtz(p[jt * 4 + 0], p[jt * 4 + 1]);
      auto hi = __builtin_amdgcn_cvt_pkrtz(p[jt * 4 + 2], p[jt * 4 + 3]);
      f16x4 pk = { (f16)lo[0], (f16)lo[1], (f16)hi[0], (f16)hi[1] };
      *(f16x4*)&PL[buf][wv * 16 + cl][jt * 16 + g * 4] = pk;
    }
    if (ln == 0) rsF[buf][wv] = wflag;
    // attn0 embed: wave 0 of qt==0 blocks, lanes cl==0 hold P[0][j]
    if (isA0) {
      if (ln == 0) mHist[kt] = m_run;
      if (cl == 0) {
#pragma unroll
        for (int jt = 0; jt < 4; ++jt) {
          float4 pw = { p[jt * 4 + 0], p[jt * 4 + 1],
                        p[jt * 4 + 2], p[jt * 4 + 3] };
          *(float4*)(a0base + kt * 64 + jt * 16 + g * 4) = pw;
        }
      }
    }
  };

  // ---- Xt B-frag loads for PV tile kt ----
  auto XFLOAD = [&](int kt) {
#pragma unroll
    for (int ks2 = 0; ks2 < 2; ++ks2)
#pragma unroll
      for (int ddt = 0; ddt < 4; ++ddt)
        xf[ks2][ddt] = *(const f16x8*)(xb + (size_t)(ddt * 16 + cl) * 2048 +
                                       kt * 64 + ks2 * 32 + g * 8);
  };

  // ---- PV for PL[pbuf] (lagged tile), with gated rescale ----
  auto PVDO = [&](int pbuf) {
    int4 fl = *(const int4*)&rsF[pbuf][0];
    int flq[4] = { fl.x, fl.y, fl.z, fl.w };
#pragma unroll
    for (int qt2 = 0; qt2 < 4; ++qt2) {
      if (flq[qt2]) {
        f32x4 a4 = *(const f32x4*)&alphaL[pbuf][qt2 * 16 + g * 4];
#pragma unroll
        for (int ddt = 0; ddt < 4; ++ddt)
#pragma unroll
          for (int r = 0; r < 4; ++r) acc[qt2][ddt][r] *= a4[r];
      }
    }
#pragma unroll
    for (int ks2 = 0; ks2 < 2; ++ks2) {
      f16x8 pf[4];
#pragma unroll
      for (int qt2 = 0; qt2 < 4; ++qt2)
        pf[qt2] = *(const f16x8*)&PL[pbuf][qt2 * 16 + cl][ks2 * 32 + g * 8];
#pragma unroll
      for (int ddt = 0; ddt < 4; ++ddt)
#pragma unroll
        for (int qt2 = 0; qt2 < 4; ++qt2)
          acc[qt2][ddt] = __builtin_amdgcn_mfma_f32_16x16x32_f16(
              pf[qt2], xf[ks2][ddt], acc[qt2][ddt], 0, 0, 0);
    }
  };

  // ---- prologue: stage K tile 0 ----
  *(f16x8*)&KaL[0][krow][koff] = *(const f16x8*)kaSrc;
  *(f16x8*)&KsL[0][krow][koff] = *(const f16x8*)ksSrc;
  __syncthreads();

  // I_0: score(0) only; commit K(1)
  f16x8 kan = *(const f16x8*)(kaSrc + 2048);
  f16x8 ksn = *(const f16x8*)(ksSrc + 2048);
  SCORE_MM(0);
  SCORE_FIN(0, 0);
  *(f16x8*)&KaL[1][krow][koff] = kan;
  *(f16x8*)&KsL[1][krow][koff] = ksn;
  __syncthreads();

  // main loop: interval k = score(k) + PV(k-1)
  for (int k = 1; k < 32; ++k) {
    int sbuf = k & 1, pbuf = sbuf ^ 1;
    XFLOAD(k - 1);                           // global loads in flight early
    if (k < 31) {
      kan = *(const f16x8*)(kaSrc + (size_t)(k + 1) * 2048);
      ksn = *(const f16x8*)(ksSrc + (size_t)(k + 1) * 2048);
    }
    __builtin_amdgcn_s_setprio(1);           // favor this block's MFMA burst
    SCORE_MM(sbuf);                          // 8 MFMA (current tile)
    PVDO(pbuf);                              // 32 MFMA (lagged tile)
    __builtin_amdgcn_s_setprio(0);
    SCORE_FIN(sbuf, k);                      // softmax VALU overlaps pipe drain
    if (k < 31) {
      *(f16x8*)&KaL[pbuf][krow][koff] = kan;
      *(f16x8*)&KsL[pbuf][krow][koff] = ksn;
    }
    __syncthreads();
  }

  // drain: PV tile 31 (PL buffer 1)
  XFLOAD(31);
  __builtin_amdgcn_s_setprio(1);
  PVDO(1);
  __builtin_amdgcn_s_setprio(0);

  // l reduction (deferred): once per kernel instead of per tile
  l_lane += __shfl_xor(l_lane, 16, 64);
  l_lane += __shfl_xor(l_lane, 32, 64);
  if (g == 0) lL[wv * 16 + cl] = l_lane;
  if (isA0 && ln == 0) mFinS = m_run;        // row-0 final max (raw domain)
  __syncthreads();
#pragma unroll
  for (int qt2 = 0; qt2 < 4; ++qt2) {
#pragma unroll
    for (int r = 0; r < 4; ++r) {
      float linv = 1.0f / lL[qt2 * 16 + g * 4 + r];
      int q = qt * 64 + qt2 * 16 + g * 4 + r;
#pragma unroll
      for (int ddt = 0; ddt < 4; ++ddt) {
        float v = acc[qt2][ddt][r] * linv;
        int col = h * 256 + wv * 64 + ddt * 16 + cl;
        out[((size_t)b * 2048 + q) * 2048 + col] = v;
        if (q == 0) out_cls[(size_t)b * 2048 + col] = v;
      }
    }
  }
  // attn0 fix-up: rescale raw p by 2^((m_tile-m_fin)*SCL)/l0, in place
  if (qt == 0) {
    float l0inv = 1.0f / lL[0];
    float mf = mFinS;
    for (int i = t; i < 2048; i += 256) {
      float v = a0base[i];
      a0base[i] = v * exp2f((mHist[i >> 6] - mf) * SCL) * l0inv;
    }
  }
}

extern "C" void kernel_launch(void* const* d_in, const int* in_sizes, int n_in,
                              void* d_out, int out_size, void* d_ws, size_t ws_size,
                              hipStream_t stream) {
  const float* x  = (const float*)d_in[0];
  const float* af = (const float*)d_in[1];
  const float* Wq = (const float*)d_in[2];
  const float* Wa = (const float*)d_in[3];
  // ws (f16): Qs|Ks|Qa|Ka (4x1M) | xt (1M) | Wt (256K)  ~= 10.5 MB
  const size_t QK = (size_t)2 * 8 * 2048 * 32;
  f16* Qs = (f16*)d_ws;
  f16* Ks = Qs + QK;
  f16* Qa = Ks + QK;
  f16* Ka = Qa + QK;
  f16* xt = Ka + QK;
  f16* Wt = xt + QK;
  float* out     = (float*)d_out;
  float* out_cls = out + (size_t)2 * 2048 * 2048;
  float* attn0   = out_cls + 2 * 2048;

  k_W<<<dim3(8, 4, 2), 256, 0, stream>>>(Wq, Wa, Wt);
  k_proj<<<dim3(80, 8, 2), 256, 0, stream>>>(x, af, Wt, Qs, Ks, Qa, Ka, xt);
  k_flash<<<dim3(32, 8, 2), 256, 0, stream>>>(Qs, Ks, Qa, Ka, xt, out, out_cls,
                                              attn0);
}